// Round 1
// baseline (2306.456 us; speedup 1.0000x reference)
//
#include <hip/hip_runtime.h>

// b=64, c=d=512, hw=4096, n=32, M=b*n=2048, 3 slot-attention iterations.
// x(64,512,4096) fp32, j-contiguous.
// This version: one-time transposes xT[b][j][d] (512MB) and WqT[k][o] (1MB)
// so ALL three GEMMs stage their B-operand with async global_load_lds width=16
// (wave-uniform LDS dest + 1KB contiguous rows). No scalar ds_write transposes
// remain in the per-iteration hot path.

#define F4(p)  (*reinterpret_cast<float4*>(p))
#define CF4(p) (*reinterpret_cast<const float4*>(p))

// stats buffer float offsets
#define O_SUM1 0
#define O_SQ1  512
#define O_SUM2 1024
#define O_SQ2  1056
#define O_SC1  1088
#define O_SH1  1600
#define O_SC2  2112
#define O_SH2  2144
#define O_RS   2176   // rowsum[2048]

typedef __attribute__((address_space(1))) const void gvoid_t;
typedef __attribute__((address_space(3))) void lvoid_t;
__device__ __forceinline__ void gload_lds16(const float* g, float* l) {
    // async global->LDS, 16B/lane; LDS dest = wave-uniform base + lane*16
    __builtin_amdgcn_global_load_lds((gvoid_t*)g, (lvoid_t*)l, 16, 0, 0);
}

// ---------------- one-time 64x64-tile transpose: A[R][C] -> AT[C][R] ----------------
// batch over blockIdx.z (stride R*C both sides). Coalesced 256B segments both ways.
__global__ __launch_bounds__(256) void k_transpose64(const float* __restrict__ A,
                                                     float* __restrict__ AT,
                                                     int R, int C) {
    __shared__ __align__(16) float tile[64][68];
    const int cb = blockIdx.x * 64;          // column tile (fast dim of A)
    const int rb = blockIdx.y * 64;          // row tile
    const size_t bofs = (size_t)blockIdx.z * R * C;
    const float* Ab = A + bofs;
    float* ATb = AT + bofs;
    const int t = threadIdx.x;
    const int g = t >> 4, h = t & 15;        // g: row-group 0..15, h: col-quad 0..15
    // load 4 rows x 4 cols micro-tile, transpose in registers
    float4 v0 = CF4(Ab + (size_t)(rb + g * 4 + 0) * C + cb + h * 4);
    float4 v1 = CF4(Ab + (size_t)(rb + g * 4 + 1) * C + cb + h * 4);
    float4 v2 = CF4(Ab + (size_t)(rb + g * 4 + 2) * C + cb + h * 4);
    float4 v3 = CF4(Ab + (size_t)(rb + g * 4 + 3) * C + cb + h * 4);
    float4 w0 = {v0.x, v1.x, v2.x, v3.x};
    float4 w1 = {v0.y, v1.y, v2.y, v3.y};
    float4 w2 = {v0.z, v1.z, v2.z, v3.z};
    float4 w3 = {v0.w, v1.w, v2.w, v3.w};
    F4(&tile[h * 4 + 0][g * 4]) = w0;
    F4(&tile[h * 4 + 1][g * 4]) = w1;
    F4(&tile[h * 4 + 2][g * 4]) = w2;
    F4(&tile[h * 4 + 3][g * 4]) = w3;
    __syncthreads();
#pragma unroll
    for (int s = 0; s < 4; ++s) {
        int crow = g + 16 * s;
        F4(ATb + (size_t)(cb + crow) * R + rb + h * 4) = F4(&tile[crow][h * 4]);
    }
}

// ---------------- init / blend / zero ----------------
__global__ void k_init_slots(const float* __restrict__ meta, float* __restrict__ slots) {
    int f = blockIdx.x * 256 + threadIdx.x;      // float4 index, 262144
    int m = f >> 7;
    int d4 = f & 127;
    F4(slots + (size_t)f * 4) = CF4(meta + ((size_t)((m & 31) << 7) + d4) * 4);
}

__global__ void k_blend(float* __restrict__ slots, const float* __restrict__ ns) {
    int f = blockIdx.x * 256 + threadIdx.x;
    float4 s = F4(slots + (size_t)f * 4);
    float4 n = CF4(ns + (size_t)f * 4);
    s.x = 0.9f * s.x + 0.1f * n.x;
    s.y = 0.9f * s.y + 0.1f * n.y;
    s.z = 0.9f * s.z + 0.1f * n.z;
    s.w = 0.9f * s.w + 0.1f * n.w;
    F4(slots + (size_t)f * 4) = s;
}

// q[m][n] = bq[n]  (bias folded into init; qgemm atomicAdds partial sums)
__global__ void k_qinit(const float* __restrict__ bq, float* __restrict__ Q) {
    int f = blockIdx.x * 256 + threadIdx.x;   // 262144 float4
    F4(Q + (size_t)f * 4) = CF4(bq + (size_t)(f & 127) * 4);
}

__global__ void k_zero_out(float* __restrict__ out) {
    int f = blockIdx.x * 256 + threadIdx.x;   // 262144 float4
    float4 z = {0.f, 0.f, 0.f, 0.f};
    F4(out + (size_t)f * 4) = z;
}

// ---------------- qgemm: q[m,o] += sum_k slots[m,k]*WqT[k,o], K-split x4 ----------------
// grid (64 m-tiles of 32, 4 k-splits), 256 thr, 8x8/thread, block covers 32m x 512n.
// B-tile now staged async from WqT (k-major rows contiguous in o).
__global__ __launch_bounds__(256) void k_qgemm(const float* __restrict__ S,
                                               const float* __restrict__ WqT,
                                               float* __restrict__ Q) {
    __shared__ __align__(16) float asT[32][36];    // [k][m]
    __shared__ __align__(16) float bs[32][512];    // [k][n] direct layout (gload_lds)
    const int m0 = blockIdx.x * 32;
    const int kbase = blockIdx.y * 128;
    const int t = threadIdx.x;
    const int w = t >> 6, l = t & 63;
    const int ty = w, tx = l;
    float c[8][8] = {};
    for (int ch = 0; ch < 4; ++ch) {
        int k0 = kbase + ch * 32;
        {   // slots tile 32m x 32k -> asT[k][m]
            int m = t >> 3, kq = t & 7;
            float4 v = CF4(S + (size_t)(m0 + m) * 512 + k0 + kq * 4);
            asT[kq * 4 + 0][m] = v.x; asT[kq * 4 + 1][m] = v.y;
            asT[kq * 4 + 2][m] = v.z; asT[kq * 4 + 3][m] = v.w;
        }
        // WqT tile 32k x 512n: async 1KB chunks, wave-uniform LDS dest
#pragma unroll
        for (int cc = 0; cc < 16; ++cc) {
            int chunk = w * 16 + cc;          // 0..63
            int row = chunk >> 1, half = chunk & 1;
            const float* src = WqT + (size_t)(k0 + row) * 512 + half * 256 + l * 4;
            gload_lds16(src, &bs[row][half * 256]);
        }
        __syncthreads();
#pragma unroll 8
        for (int k = 0; k < 32; ++k) {
            float4 a0 = F4(&asT[k][ty * 8]);
            float4 a1 = F4(&asT[k][ty * 8 + 4]);
            float4 b0 = F4(&bs[k][tx * 4]);
            float4 b1 = F4(&bs[k][256 + tx * 4]);
            float av[8] = {a0.x, a0.y, a0.z, a0.w, a1.x, a1.y, a1.z, a1.w};
            float bv[8] = {b0.x, b0.y, b0.z, b0.w, b1.x, b1.y, b1.z, b1.w};
#pragma unroll
            for (int ii = 0; ii < 8; ++ii)
#pragma unroll
                for (int jj = 0; jj < 8; ++jj)
                    c[ii][jj] = fmaf(av[ii], bv[jj], c[ii][jj]);
        }
        __syncthreads();
    }
#pragma unroll
    for (int ii = 0; ii < 8; ++ii) {
        float* dst = Q + (size_t)(m0 + ty * 8 + ii) * 512;
#pragma unroll
        for (int q = 0; q < 4; ++q) atomicAdd(dst + tx * 4 + q, c[ii][q]);
#pragma unroll
        for (int q = 0; q < 4; ++q) atomicAdd(dst + 256 + tx * 4 + q, c[ii][4 + q]);
    }
}

// ---------------- BN1 ----------------
__global__ void k_zero_stats(float* __restrict__ stats) {
    int i = blockIdx.x * 256 + threadIdx.x;
    if (i < 1088) stats[i] = 0.0f;
}

__global__ __launch_bounds__(256) void k_bn1_stats(const float* __restrict__ Q,
                                                   float* __restrict__ stats) {
    int cg = blockIdx.x & 7, rc = blockIdx.x >> 3;
    int lc = threadIdx.x & 63;
    int col = cg * 64 + lc;
    int rsub = threadIdx.x >> 6;
    float s = 0.f, sq = 0.f;
    for (int k = 0; k < 64; ++k) {
        float v = Q[(size_t)(rc * 256 + rsub + 4 * k) * 512 + col];
        s += v;
        sq += v * v;
    }
    __shared__ float ls[4][64], lq[4][64];
    ls[rsub][lc] = s;
    lq[rsub][lc] = sq;
    __syncthreads();
    if (threadIdx.x < 64) {
        int tcol = threadIdx.x;
        float ts = ls[0][tcol] + ls[1][tcol] + ls[2][tcol] + ls[3][tcol];
        float tq = lq[0][tcol] + lq[1][tcol] + lq[2][tcol] + lq[3][tcol];
        atomicAdd(&stats[O_SUM1 + cg * 64 + tcol], ts);
        atomicAdd(&stats[O_SQ1 + cg * 64 + tcol], tq);
    }
}

__global__ void k_bn1_fin(float* __restrict__ stats, const float* __restrict__ g1,
                          const float* __restrict__ b1) {
    int c = threadIdx.x;
    float mean = stats[O_SUM1 + c] * (1.0f / 2048.0f);
    float var = stats[O_SQ1 + c] * (1.0f / 2048.0f) - mean * mean;
    float sc = rsqrtf(var + 1e-5f) * g1[c];
    stats[O_SC1 + c] = sc;
    stats[O_SH1 + c] = b1[c] - mean * sc;
}

__global__ void k_bn1_apply(float* __restrict__ Q, const float* __restrict__ stats) {
    int f = blockIdx.x * 256 + threadIdx.x;
    int col4 = f & 127;
    float4 v = F4(Q + (size_t)f * 4);
    float4 sc = CF4(stats + O_SC1 + col4 * 4);
    float4 sh = CF4(stats + O_SH1 + col4 * 4);
    v.x = fmaxf(fmaf(v.x, sc.x, sh.x), 0.f);
    v.y = fmaxf(fmaf(v.y, sc.y, sh.y), 0.f);
    v.z = fmaxf(fmaf(v.z, sc.z, sh.z), 0.f);
    v.w = fmaxf(fmaf(v.w, sc.w, sh.w), 0.f);
    F4(Q + (size_t)f * 4) = v;
}

// ---------------- GEMM1: attn[b,i,j] = sum_k q[b*32+i,k]*x[b,k,j] ----------------
// grid (8 j-tiles of 512, 64 b), 256 thr. Per-thread 8i x (4j + 4j@+256).
__global__ __launch_bounds__(256) void k_gemm1(const float* __restrict__ Q,
                                               const float* __restrict__ X,
                                               float* __restrict__ attn) {
    __shared__ __align__(16) float qsT[32][36];   // [k][i]
    __shared__ __align__(16) float xs[32][512];   // [k][j] direct layout
    const int b = blockIdx.y;
    const int j0 = blockIdx.x * 512;
    const int t = threadIdx.x;
    const int w = t >> 6, l = t & 63;
    const int ty = w, tx = l;
    const float* qb = Q + (size_t)b * 32 * 512;
    const float* xb = X + (size_t)b * 512 * 4096 + j0;
    float c[8][8] = {};
    for (int k0 = 0; k0 < 512; k0 += 32) {
        {   // q tile 32i x 32k -> qsT[k][i]
            int i = t >> 3, kq = t & 7;
            float4 v = CF4(qb + (size_t)i * 512 + k0 + kq * 4);
            qsT[kq * 4 + 0][i] = v.x; qsT[kq * 4 + 1][i] = v.y;
            qsT[kq * 4 + 2][i] = v.z; qsT[kq * 4 + 3][i] = v.w;
        }
        // x tile 32k x 512j: async 1KB chunks, wave-uniform LDS dest
#pragma unroll
        for (int cc = 0; cc < 16; ++cc) {
            int chunk = w * 16 + cc;          // 0..63
            int row = chunk >> 1, half = chunk & 1;
            const float* src = xb + (size_t)(k0 + row) * 4096 + half * 256 + l * 4;
            gload_lds16(src, &xs[row][half * 256]);
        }
        __syncthreads();
#pragma unroll 8
        for (int k = 0; k < 32; ++k) {
            float4 a0 = F4(&qsT[k][ty * 8]);
            float4 a1 = F4(&qsT[k][ty * 8 + 4]);
            float4 b0 = F4(&xs[k][tx * 4]);
            float4 b1 = F4(&xs[k][256 + tx * 4]);
            float av[8] = {a0.x, a0.y, a0.z, a0.w, a1.x, a1.y, a1.z, a1.w};
            float bv[8] = {b0.x, b0.y, b0.z, b0.w, b1.x, b1.y, b1.z, b1.w};
#pragma unroll
            for (int ii = 0; ii < 8; ++ii)
#pragma unroll
                for (int jj = 0; jj < 8; ++jj)
                    c[ii][jj] = fmaf(av[ii], bv[jj], c[ii][jj]);
        }
        __syncthreads();
    }
#pragma unroll
    for (int ii = 0; ii < 8; ++ii) {
        float* dst = attn + (size_t)(b * 32 + ty * 8 + ii) * 4096 + j0;
        float4 r0 = {c[ii][0], c[ii][1], c[ii][2], c[ii][3]};
        float4 r1 = {c[ii][4], c[ii][5], c[ii][6], c[ii][7]};
        F4(dst + tx * 4) = r0;
        F4(dst + 256 + tx * 4) = r1;
    }
}

// ---------------- BN2 ----------------
__global__ __launch_bounds__(256) void k_bn2_stats(const float* __restrict__ attn,
                                                   float* __restrict__ stats) {
    int i = blockIdx.x, b = blockIdx.y;
    const float* p = attn + (size_t)(b * 32 + i) * 4096;
    int t = threadIdx.x;
    float s = 0.f, sq = 0.f;
#pragma unroll
    for (int c = 0; c < 4; ++c) {
        float4 v = CF4(p + (size_t)(t + 256 * c) * 4);
        s += v.x + v.y + v.z + v.w;
        sq += v.x * v.x + v.y * v.y + v.z * v.z + v.w * v.w;
    }
    __shared__ float rs[256], rq[256];
    rs[t] = s; rq[t] = sq;
    __syncthreads();
    for (int off = 128; off > 0; off >>= 1) {
        if (t < off) { rs[t] += rs[t + off]; rq[t] += rq[t + off]; }
        __syncthreads();
    }
    if (t == 0) {
        atomicAdd(&stats[O_SUM2 + i], rs[0]);
        atomicAdd(&stats[O_SQ2 + i], rq[0]);
    }
}

__global__ void k_bn2_fin(float* __restrict__ stats, const float* __restrict__ g2,
                          const float* __restrict__ b2) {
    int i = threadIdx.x;
    const float inv = 1.0f / 262144.0f;
    float mean = stats[O_SUM2 + i] * inv;
    float var = stats[O_SQ2 + i] * inv - mean * mean;
    float sc = rsqrtf(var + 1e-5f) * g2[i];
    stats[O_SC2 + i] = sc;
    stats[O_SH2 + i] = b2[i] - mean * sc;
}

__global__ __launch_bounds__(256) void k_bn2_apply(float* __restrict__ attn,
                                                   float* __restrict__ stats) {
    int i = blockIdx.x, b = blockIdx.y;
    float* p = attn + (size_t)(b * 32 + i) * 4096;
    float sc = stats[O_SC2 + i], sh = stats[O_SH2 + i];
    int t = threadIdx.x;
    float s = 0.f;
#pragma unroll
    for (int c = 0; c < 4; ++c) {
        float4 v = F4(p + (size_t)(t + 256 * c) * 4);
        v.x = fmaxf(fmaf(v.x, sc, sh), 0.f);
        v.y = fmaxf(fmaf(v.y, sc, sh), 0.f);
        v.z = fmaxf(fmaf(v.z, sc, sh), 0.f);
        v.w = fmaxf(fmaf(v.w, sc, sh), 0.f);
        s += v.x + v.y + v.z + v.w;
        F4(p + (size_t)(t + 256 * c) * 4) = v;
    }
    __shared__ float rs[256];
    rs[t] = s;
    __syncthreads();
    for (int off = 128; off > 0; off >>= 1) {
        if (t < off) rs[t] += rs[t + off];
        __syncthreads();
    }
    if (t == 0) stats[O_RS + b * 32 + i] = rs[0];
}

// ---------------- GEMM2: out[b*32+i,d] += sum_{j in split} attn[b,i,j]*xT[b,j,d]*inv_rs ----------------
// grid (8 j-splits of 512, 64 b), 256 thr. Now structurally identical to gemm1:
// B-tile (xT rows, d-contiguous) staged async via global_load_lds, no scalar transpose.
__global__ __launch_bounds__(256) void k_gemm2(const float* __restrict__ attn,
                                               const float* __restrict__ XT,
                                               const float* __restrict__ stats,
                                               float* __restrict__ out) {
    __shared__ __align__(16) float asT[32][36];   // [j][i]
    __shared__ __align__(16) float xs[32][512];   // [j][d] direct layout
    const int b = blockIdx.y;
    const int jbase0 = blockIdx.x * 512;
    const int t = threadIdx.x;
    const int w = t >> 6, l = t & 63;
    const int ty = w, tx = l;
    const float* ab = attn + (size_t)b * 32 * 4096 + jbase0;
    const float* xb = XT + (size_t)b * 4096 * 512 + (size_t)jbase0 * 512;
    float c[8][8] = {};
    for (int ch = 0; ch < 16; ++ch) {
        int jb = ch * 32;
        {   // attn tile 32i x 32j -> asT[j][i]
            int i = t >> 3, jq = t & 7;
            float4 v = CF4(ab + (size_t)i * 4096 + jb + jq * 4);
            asT[jq * 4 + 0][i] = v.x; asT[jq * 4 + 1][i] = v.y;
            asT[jq * 4 + 2][i] = v.z; asT[jq * 4 + 3][i] = v.w;
        }
        // xT tile 32j x 512d: async 1KB chunks, wave-uniform LDS dest
#pragma unroll
        for (int cc = 0; cc < 16; ++cc) {
            int chunk = w * 16 + cc;          // 0..63
            int row = chunk >> 1, half = chunk & 1;
            const float* src = xb + (size_t)(jb + row) * 512 + half * 256 + l * 4;
            gload_lds16(src, &xs[row][half * 256]);
        }
        __syncthreads();
#pragma unroll 8
        for (int k = 0; k < 32; ++k) {
            float4 a0 = F4(&asT[k][ty * 8]);
            float4 a1 = F4(&asT[k][ty * 8 + 4]);
            float4 b0 = F4(&xs[k][tx * 4]);
            float4 b1 = F4(&xs[k][256 + tx * 4]);
            float av[8] = {a0.x, a0.y, a0.z, a0.w, a1.x, a1.y, a1.z, a1.w};
            float bv[8] = {b0.x, b0.y, b0.z, b0.w, b1.x, b1.y, b1.z, b1.w};
#pragma unroll
            for (int ii = 0; ii < 8; ++ii)
#pragma unroll
                for (int jj = 0; jj < 8; ++jj)
                    c[ii][jj] = fmaf(av[ii], bv[jj], c[ii][jj]);
        }
        __syncthreads();
    }
#pragma unroll
    for (int ii = 0; ii < 8; ++ii) {
        int row = b * 32 + ty * 8 + ii;
        float inv = 1.0f / (stats[O_RS + row] + 1e-12f);
        float* dst = out + (size_t)row * 512;
#pragma unroll
        for (int q = 0; q < 4; ++q) atomicAdd(dst + tx * 4 + q, c[ii][q] * inv);
#pragma unroll
        for (int q = 0; q < 4; ++q) atomicAdd(dst + 256 + tx * 4 + q, c[ii][4 + q] * inv);
    }
}

extern "C" void kernel_launch(void* const* d_in, const int* in_sizes, int n_in,
                              void* d_out, int out_size, void* d_ws, size_t ws_size,
                              hipStream_t stream) {
    const float* x    = (const float*)d_in[0];
    const float* meta = (const float*)d_in[1];
    const float* Wq   = (const float*)d_in[2];
    const float* bq   = (const float*)d_in[3];
    const float* g1   = (const float*)d_in[4];
    const float* b1   = (const float*)d_in[5];
    const float* g2   = (const float*)d_in[6];
    const float* b2   = (const float*)d_in[7];
    float* out = (float*)d_out;

    float* ws = (float*)d_ws;
    float* slots = ws;                  // 1048576 floats (4 MB)
    float* q     = ws + 1048576;        // 1048576 floats (4 MB)
    float* attn  = ws + 2097152;        // 8388608 floats (32 MB)
    float* stats = ws + 10485760;       // 4224 floats
    float* wqT   = ws + 10489984;       // 262144 floats (1 MB)
    float* xT    = ws + 16777216;       // 134217728 floats (512 MB); ws is 2 GiB

    // one-time transposes (amortized over the 3 iterations)
    k_transpose64<<<dim3(8, 8, 1), 256, 0, stream>>>(Wq, wqT, 512, 512);
    k_transpose64<<<dim3(64, 8, 64), 256, 0, stream>>>(x, xT, 512, 4096);

    k_init_slots<<<1024, 256, 0, stream>>>(meta, slots);
    for (int it = 0; it < 3; ++it) {
        if (it > 0) k_blend<<<1024, 256, 0, stream>>>(slots, out);
        k_qinit<<<1024, 256, 0, stream>>>(bq, q);
        k_qgemm<<<dim3(64, 4), 256, 0, stream>>>(slots, wqT, q);
        k_zero_stats<<<5, 256, 0, stream>>>(stats);
        k_bn1_stats<<<64, 256, 0, stream>>>(q, stats);
        k_bn1_fin<<<1, 512, 0, stream>>>(stats, g1, b1);
        k_bn1_apply<<<1024, 256, 0, stream>>>(q, stats);
        k_gemm1<<<dim3(8, 64), 256, 0, stream>>>(q, x, attn);
        k_bn2_stats<<<dim3(32, 64), 256, 0, stream>>>(attn, stats);
        k_bn2_fin<<<1, 32, 0, stream>>>(stats, g2, b2);
        k_bn2_apply<<<dim3(32, 64), 256, 0, stream>>>(attn, stats);
        k_zero_out<<<1024, 256, 0, stream>>>(out);
        k_gemm2<<<dim3(8, 64), 256, 0, stream>>>(attn, xT, stats, out);
    }
}